// Round 7
// baseline (481.548 us; speedup 1.0000x reference)
//
#include <hip/hip_runtime.h>

// GraphConvolution (Chebyshev K=5) on MI355X — round 7.
// Keeps round-6's XCD-sliced data placement ([8][M][32] bf16, slice=blockIdx&7,
// gathers L2-resident, FETCH ~= compulsory). Replaces the SpMM compute shape:
//   - lane = (row r, feature chunk q): per-lane local accumulation ->
//     NO cross-lane reduce (was 96 shfl/row), store = plain 8-B write
//   - degree-sorted row permutation (64-bin counting sort in prep) -> rows in
//     a wave have ~equal degree; uniform branch-free edge loop (cndmask pad)
//   - 2 edges unrolled, all iterations independent -> deep pipelining
//   - y stores nontemporal (keep L2 for the gather slice + cv)

constexpr int M   = 49152;
constexpr int B   = 16;
constexpr int FIN = 16;
constexpr int F1  = 32;
constexpr int K   = 5;
constexpr int XBS = M * FIN;                 // per-b stride in x[B,M,FIN]
constexpr size_t SLICEB   = (size_t)M * 64;  // bytes per feature slice
constexpr size_t BUFBYTES = (size_t)M * 512; // bytes per xs_k buffer (8 slices)

typedef short s16x8 __attribute__((ext_vector_type(8)));
typedef float f32x4 __attribute__((ext_vector_type(4)));
typedef unsigned int u32;
typedef unsigned long long u64;

#define DEVFN __device__ __forceinline__

DEVFN float lo2f(u32 d) {
  union { u32 u; float f; } v; v.u = d << 16; return v.f;
}
DEVFN float hi2f(u32 d) {
  union { u32 u; float f; } v; v.u = d & 0xffff0000u; return v.f;
}
DEVFN unsigned short f2bf(float f) {   // round-to-nearest-even
  union { float f; u32 u; } v;
  v.f = f;
  u32 r = (v.u + 0x7FFFu + ((v.u >> 16) & 1u)) >> 16;
  return (unsigned short)r;
}

// ---------------- x -> bf16 slice-major [8][M][32] ----------------

__global__ __launch_bounds__(256) void transform_x(const float* __restrict__ x,
                                                   char* __restrict__ x0b) {
  int lane = threadIdx.x & 63;
  int m = blockIdx.x * 4 + (threadIdx.x >> 6);
  int s = lane >> 3, i = lane & 7;
  int b = 2 * s + (i >> 2), f = (i & 3) * 4;
  float4 v = *(const float4*)(x + (size_t)b * XBS + (size_t)m * FIN + f);
  ushort4 r = make_ushort4(f2bf(v.x), f2bf(v.y), f2bf(v.z), f2bf(v.w));
  *(ushort4*)(x0b + (size_t)s * SLICEB + (size_t)m * 64 + i * 8) = r;
}

// ---------------- CSR build ----------------

__global__ __launch_bounds__(256) void hist_kernel(const int* __restrict__ rows,
                                                   int* __restrict__ counts, int nnz) {
  int i = blockIdx.x * 256 + threadIdx.x;
  if (i < nnz) atomicAdd(&counts[rows[i]], 1);
}

DEVFN int wave_incl_scan(int v, int lane) {
#pragma unroll
  for (int off = 1; off < 64; off <<= 1) {
    int t = __shfl_up(v, off);
    if (lane >= off) v += t;
  }
  return v;
}

__global__ __launch_bounds__(1024) void scan_blocks(const int* __restrict__ counts,
                                                    int* __restrict__ row_ptr,
                                                    int* __restrict__ partials) {
  __shared__ int wsum[16];
  int tid = threadIdx.x, lane = tid & 63, w = tid >> 6;
  int i = blockIdx.x * 1024 + tid;
  int s = wave_incl_scan(counts[i], lane);
  if (lane == 63) wsum[w] = s;
  __syncthreads();
  if (tid < 16) {
    int t = wsum[tid];
#pragma unroll
    for (int off = 1; off < 16; off <<= 1) {
      int u = __shfl_up(t, off);
      if (tid >= off) t += u;
    }
    wsum[tid] = t;
  }
  __syncthreads();
  int base = (w > 0) ? wsum[w - 1] : 0;
  s += base;
  row_ptr[i + 1] = s;
  if (tid == 1023) partials[blockIdx.x] = s;
}

__global__ void scan_partials_kernel(int* __restrict__ partials,
                                     int* __restrict__ row_ptr, int nblk) {
  int lane = threadIdx.x;  // 64 threads
  int v = (lane < nblk) ? partials[lane] : 0;
  v = wave_incl_scan(v, lane);
  if (lane < nblk) partials[lane] = v;
  if (lane == 0) row_ptr[0] = 0;
}

__global__ __launch_bounds__(1024) void scan_add_kernel(int* __restrict__ row_ptr,
                                                        const int* __restrict__ partials) {
  if (blockIdx.x == 0) return;
  int i = blockIdx.x * 1024 + threadIdx.x;
  row_ptr[i + 1] += partials[blockIdx.x - 1];
}

// cv entry: col (high 16) | val-bf16 (low 16)
__global__ __launch_bounds__(256) void scatter_kernel(const int* __restrict__ rows,
                                                      const int* __restrict__ cols,
                                                      const float* __restrict__ vals,
                                                      const int* __restrict__ row_ptr,
                                                      int* __restrict__ fill,
                                                      u32* __restrict__ cvp, int nnz) {
  int i = blockIdx.x * 256 + threadIdx.x;
  if (i < nnz) {
    int r = rows[i];
    int pos = row_ptr[r] + atomicAdd(&fill[r], 1);
    cvp[pos] = ((u32)cols[i] << 16) | (u32)f2bf(vals[i]);
  }
}

// ---------------- degree-sort (counting sort, 64 bins) ----------------

__global__ __launch_bounds__(256) void deg_hist(const int* __restrict__ counts,
                                                int* __restrict__ dhist) {
  __shared__ int lh[64];
  int tid = threadIdx.x;
  if (tid < 64) lh[tid] = 0;
  __syncthreads();
  int m = blockIdx.x * 256 + tid;
  atomicAdd(&lh[min(counts[m], 63)], 1);
  __syncthreads();
  if (tid < 64 && lh[tid]) atomicAdd(&dhist[tid], lh[tid]);
}

__global__ void deg_scan(const int* __restrict__ dhist, int* __restrict__ dbase) {
  int lane = threadIdx.x;   // 64 threads
  int v = dhist[lane];
  int s = wave_incl_scan(v, lane);
  dbase[lane] = s - v;      // exclusive
}

__global__ __launch_bounds__(256) void perm_scatter(const int* __restrict__ counts,
                                                    const int* __restrict__ dbase,
                                                    int* __restrict__ dcur,
                                                    int* __restrict__ perm) {
  int m = blockIdx.x * 256 + threadIdx.x;
  int d = min(counts[m], 63);
  int pos = dbase[d] + atomicAdd(&dcur[d], 1);
  perm[pos] = m;
}

// ---------------- SpMM: XCD-sliced, reduce-free ----------------
// slice s = blockIdx&7 (-> XCD). Wave = 8 rows x 8 feature-chunks; lane
// (r = lane>>3, q = lane&7) owns features q*4..q*4+3 of row perm[grp*8+r]
// and accumulates them locally over the row's edges. Degree-sorted perm ->
// wmax ~= deg for all 8 rows; pad iterations are cndmask'd to exact zero.

template <bool SUB>
__global__ __launch_bounds__(256) void spmm_ell(const char* __restrict__ xsrc,
                                                const char* __restrict__ ssrc,
                                                char* __restrict__ y,
                                                const int* __restrict__ row_ptr,
                                                const int* __restrict__ degs,
                                                const int* __restrict__ perm,
                                                const u32* __restrict__ cvp) {
  int s  = blockIdx.x & 7;
  int g4 = blockIdx.x >> 3;
  int lane = threadIdx.x & 63, wave = threadIdx.x >> 6;
  int r = lane >> 3, q = lane & 7;
  int grp = g4 * 4 + wave;                 // row-group (8 rows)
  const char* sbase = xsrc + (size_t)s * SLICEB;
  size_t qb = (size_t)q * 8;

  int rid  = perm[grp * 8 + r];            // 8 distinct, broadcast over q
  int base = row_ptr[rid];
  int deg  = degs[rid];
  int wmax = deg;
  wmax = max(wmax, __shfl_xor(wmax, 8));
  wmax = max(wmax, __shfl_xor(wmax, 16));
  wmax = max(wmax, __shfl_xor(wmax, 32));

  u64 sv = 0;
  if (SUB)
    sv = __builtin_nontemporal_load(
        (const u64*)(ssrc + (size_t)s * SLICEB + (size_t)rid * 64 + qb));

  float a0 = 0.f, a1 = 0.f, a2 = 0.f, a3 = 0.f;
  int t = 0;
  for (; t + 2 <= wmax; t += 2) {
    u32 c0 = cvp[base + t];
    u32 c1 = cvp[base + t + 1];
    if (t     >= deg) c0 = 0u;             // cndmask: v=0, gather row 0
    if (t + 1 >= deg) c1 = 0u;
    u64 d0 = *(const u64*)(sbase + (size_t)(c0 >> 16) * 64 + qb);
    u64 d1 = *(const u64*)(sbase + (size_t)(c1 >> 16) * 64 + qb);
    float v0 = lo2f(c0), v1 = lo2f(c1);
    u32 dl = (u32)d0, dh = (u32)(d0 >> 32);
    a0 = fmaf(v0, lo2f(dl), a0); a1 = fmaf(v0, hi2f(dl), a1);
    a2 = fmaf(v0, lo2f(dh), a2); a3 = fmaf(v0, hi2f(dh), a3);
    dl = (u32)d1; dh = (u32)(d1 >> 32);
    a0 = fmaf(v1, lo2f(dl), a0); a1 = fmaf(v1, hi2f(dl), a1);
    a2 = fmaf(v1, lo2f(dh), a2); a3 = fmaf(v1, hi2f(dh), a3);
  }
  if (t < wmax) {
    u32 c0 = cvp[base + t];
    if (t >= deg) c0 = 0u;
    u64 d0 = *(const u64*)(sbase + (size_t)(c0 >> 16) * 64 + qb);
    float v0 = lo2f(c0);
    u32 dl = (u32)d0, dh = (u32)(d0 >> 32);
    a0 = fmaf(v0, lo2f(dl), a0); a1 = fmaf(v0, hi2f(dl), a1);
    a2 = fmaf(v0, lo2f(dh), a2); a3 = fmaf(v0, hi2f(dh), a3);
  }

  if (SUB) {
    u32 sl = (u32)sv, sh = (u32)(sv >> 32);
    a0 = fmaf(2.f, a0, -lo2f(sl)); a1 = fmaf(2.f, a1, -hi2f(sl));
    a2 = fmaf(2.f, a2, -lo2f(sh)); a3 = fmaf(2.f, a3, -hi2f(sh));
  }
  u64 rv = ((u64)(((u32)f2bf(a3) << 16) | (u32)f2bf(a2)) << 32) |
           (u64)(((u32)f2bf(a1) << 16) | (u32)f2bf(a0));
  __builtin_nontemporal_store(
      rv, (u64*)(y + (size_t)s * SLICEB + (size_t)rid * 64 + qb));
}

// ---------------- Final contraction via MFMA ----------------
// out[(b*M+m)*32+o] = sum_{k,f} xs_k[m][b*16+f] * kern[(f*5+k)*32+o] + bias[o]
// kk = c*32 + g*8 + j <-> k = 2c+(g>>1), f = (g&1)*8+j; 3 chunks of K=32.
// Slice layout: feature b*16+f lives in slice b>>1 at byte (b&1)*32+f*2.

__global__ __launch_bounds__(256) void cheb_gemm_mfma(const char* __restrict__ xs0,
                                                      const float* __restrict__ kern,
                                                      const float* __restrict__ bias,
                                                      float* __restrict__ out) {
  __shared__ unsigned short bl[3][4][32][8];  // [c][g][o][j] = B_kk,o  (6 KB)
  __shared__ float bsl[32];
  int tid = threadIdx.x;
  for (int idx = tid; idx < 3 * 4 * 32 * 8; idx += 256) {
    int j = idx & 7, o = (idx >> 3) & 31, g = (idx >> 8) & 3, c = idx >> 10;
    int k = 2 * c + (g >> 1), f = (g & 1) * 8 + j;
    bl[c][g][o][j] = (k < K) ? f2bf(kern[(f * K + k) * F1 + o]) : (unsigned short)0;
  }
  if (tid < 32) bsl[tid] = bias[tid];
  __syncthreads();

  int lane = tid & 63;
  int w = blockIdx.x * 4 + (tid >> 6);     // 0..6143
  int b = w / 384;                         // 384 waves per batch b
  int mt0 = (w % 384) * 8;                 // first 16-row m-tile of 8

  int row = lane & 15, g = lane >> 4;
  int col = lane & 15;

  s16x8 bf[3][2];
#pragma unroll
  for (int c = 0; c < 3; ++c) {
#pragma unroll
    for (int ot = 0; ot < 2; ++ot)
      bf[c][ot] = *(const s16x8*)(&bl[c][g][col + 16 * ot][0]);
  }
  float bias0 = bsl[col], bias1 = bsl[col + 16];

  size_t lanebyte = (size_t)(b >> 1) * SLICEB + (size_t)row * 64 +
                    (size_t)(b & 1) * 32 + (size_t)(g & 1) * 16;
  int khalf = g >> 1;
  const char* p0 = xs0 + (size_t)(0 + khalf) * BUFBYTES + lanebyte;
  const char* p1 = xs0 + (size_t)(2 + khalf) * BUFBYTES + lanebyte;
  const char* p2 = xs0 + (size_t)(4 + khalf) * BUFBYTES + lanebyte;  // valid g<2

  size_t obase0 = ((size_t)b * M + (size_t)mt0 * 16) * F1;

#pragma unroll 2
  for (int t = 0; t < 8; ++t) {
    size_t moff = (size_t)(mt0 + t) * (16 * 64);
    s16x8 a0 = *(const s16x8*)(p0 + moff);
    s16x8 a1 = *(const s16x8*)(p1 + moff);
    s16x8 a2 = (g < 2) ? *(const s16x8*)(p2 + moff) : (s16x8)0;

    f32x4 acc0 = {0.f, 0.f, 0.f, 0.f};
    f32x4 acc1 = {0.f, 0.f, 0.f, 0.f};
    acc0 = __builtin_amdgcn_mfma_f32_16x16x32_bf16(a0, bf[0][0], acc0, 0, 0, 0);
    acc1 = __builtin_amdgcn_mfma_f32_16x16x32_bf16(a0, bf[0][1], acc1, 0, 0, 0);
    acc0 = __builtin_amdgcn_mfma_f32_16x16x32_bf16(a1, bf[1][0], acc0, 0, 0, 0);
    acc1 = __builtin_amdgcn_mfma_f32_16x16x32_bf16(a1, bf[1][1], acc1, 0, 0, 0);
    acc0 = __builtin_amdgcn_mfma_f32_16x16x32_bf16(a2, bf[2][0], acc0, 0, 0, 0);
    acc1 = __builtin_amdgcn_mfma_f32_16x16x32_bf16(a2, bf[2][1], acc1, 0, 0, 0);

    float* ob = out + obase0 + (size_t)t * (16 * F1);
#pragma unroll
    for (int j = 0; j < 4; ++j) {
      int r = g * 4 + j;
      __builtin_nontemporal_store(acc0[j] + bias0, ob + r * F1 + col);
      __builtin_nontemporal_store(acc1[j] + bias1, ob + r * F1 + col + 16);
    }
  }
}

// ---------------- launch ----------------

extern "C" void kernel_launch(void* const* d_in, const int* in_sizes, int n_in,
                              void* d_out, int out_size, void* d_ws, size_t ws_size,
                              hipStream_t stream) {
  const float* x    = (const float*)d_in[0];
  const int*   rows = (const int*)d_in[1];
  const int*   cols = (const int*)d_in[2];
  const float* vals = (const float*)d_in[3];
  const float* kern = (const float*)d_in[4];
  const float* bias = (const float*)d_in[5];
  float* out = (float*)d_out;
  int nnz = in_sizes[1];

  // workspace layout (~128 MiB); xs buffers contiguous, each slice-major.
  char* x0b = (char*)d_ws;
  char* x1b = x0b + BUFBYTES;
  char* x2b = x1b + BUFBYTES;
  char* x3b = x2b + BUFBYTES;
  char* x4b = x3b + BUFBYTES;
  int* row_ptr  = (int*)(x4b + BUFBYTES);         // M+1 (padded to M+256)
  int* counts   = row_ptr + (M + 256);            // M  (degree array)
  int* fill     = counts + M;                     // M  (scatter cursor)
  int* dcur     = fill + M;                       // 64 (perm cursor)
  int* dhist    = dcur + 64;                      // 64
  int* dbase    = dhist + 64;                     // 64
  int* partials = dbase + 64;                     // 48 (padded to 256)
  int* perm     = partials + 256;                 // M
  u32* cvp      = (u32*)(perm + M);               // NNZ+64 packed (col<<16|val)

  int nblk1024 = M / 1024;                        // 48
  int nblkM256 = M / 256;                         // 192
  int nblkNnz  = (nnz + 255) / 256;

  transform_x<<<M / 4, 256, 0, stream>>>(x, x0b);

  // zero counts+fill+dcur+dhist in one shot
  hipMemsetAsync(counts, 0, ((size_t)2 * M + 128) * 4, stream);
  hist_kernel<<<nblkNnz, 256, 0, stream>>>(rows, counts, nnz);
  scan_blocks<<<nblk1024, 1024, 0, stream>>>(counts, row_ptr, partials);
  scan_partials_kernel<<<1, 64, 0, stream>>>(partials, row_ptr, nblk1024);
  scan_add_kernel<<<nblk1024, 1024, 0, stream>>>(row_ptr, partials);
  deg_hist<<<nblkM256, 256, 0, stream>>>(counts, dhist);
  deg_scan<<<1, 64, 0, stream>>>(dhist, dbase);
  perm_scatter<<<nblkM256, 256, 0, stream>>>(counts, dbase, dcur, perm);
  scatter_kernel<<<nblkNnz, 256, 0, stream>>>(rows, cols, vals, row_ptr, fill, cvp, nnz);

  // Chebyshev recurrence (bf16, slice-major, fp32 accumulate)
  int spmmGrid = 8 * (M / 32);                    // 12288 blocks
  spmm_ell<false><<<spmmGrid, 256, 0, stream>>>(x0b, nullptr, x1b, row_ptr, counts, perm, cvp);
  spmm_ell<true ><<<spmmGrid, 256, 0, stream>>>(x1b, x0b, x2b, row_ptr, counts, perm, cvp);
  spmm_ell<true ><<<spmmGrid, 256, 0, stream>>>(x2b, x1b, x3b, row_ptr, counts, perm, cvp);
  spmm_ell<true ><<<spmmGrid, 256, 0, stream>>>(x3b, x2b, x4b, row_ptr, counts, perm, cvp);

  // final contraction + bias via MFMA: 1536 blocks x 4 waves x 8 m-tiles
  cheb_gemm_mfma<<<1536, 256, 0, stream>>>(x0b, kern, bias, out);

  (void)n_in; (void)out_size; (void)ws_size; (void)in_sizes;
}

// Round 8
// 286.310 us; speedup vs baseline: 1.6819x; 1.6819x over previous
//
#include <hip/hip_runtime.h>

// GraphConvolution (Chebyshev K=5) on MI355X — round 8.
// vs round 7:
//  (a) perm build rewritten as a contention-free counting sort:
//      per-block LDS hist -> bin-major [64][192] global scan (reuses the
//      3-kernel scan) -> per-block scatter with LDS-atomic local ranks.
//      (round 7's perm_scatter: 64 GLOBAL bins, ~10 hot -> 169.7 us, 35% of wall)
//  (b) SpMM strip-loading: lane (r,q) loads one cv word per 8 edges
//      (coalesced 32 B/row strip), 8-lane __shfl broadcast redistributes ->
//      1 cv load + 8 independent gathers in flight per wave (was 2+2);
//      inner body fully unrolled, branch-free via cvw=0 zero-padding.
// Slice placement unchanged: [8][M][32] bf16, slice = blockIdx&7 -> XCD,
// gathers L2-resident, FETCH ~= compulsory.

constexpr int M   = 49152;
constexpr int B   = 16;
constexpr int FIN = 16;
constexpr int F1  = 32;
constexpr int K   = 5;
constexpr int XBS = M * FIN;                 // per-b stride in x[B,M,FIN]
constexpr size_t SLICEB   = (size_t)M * 64;  // bytes per feature slice
constexpr size_t BUFBYTES = (size_t)M * 512; // bytes per xs_k buffer (8 slices)
constexpr int NBLK_M = M / 256;              // 192 blocks over rows
constexpr int NHB = 64 * NBLK_M;             // 12288 bin-major hist entries

typedef short s16x8 __attribute__((ext_vector_type(8)));
typedef float f32x4 __attribute__((ext_vector_type(4)));
typedef unsigned int u32;
typedef unsigned long long u64;

#define DEVFN __device__ __forceinline__

DEVFN float lo2f(u32 d) {
  union { u32 u; float f; } v; v.u = d << 16; return v.f;
}
DEVFN float hi2f(u32 d) {
  union { u32 u; float f; } v; v.u = d & 0xffff0000u; return v.f;
}
DEVFN unsigned short f2bf(float f) {   // round-to-nearest-even
  union { float f; u32 u; } v;
  v.f = f;
  u32 r = (v.u + 0x7FFFu + ((v.u >> 16) & 1u)) >> 16;
  return (unsigned short)r;
}

// ---------------- x -> bf16 slice-major [8][M][32] ----------------

__global__ __launch_bounds__(256) void transform_x(const float* __restrict__ x,
                                                   char* __restrict__ x0b) {
  int lane = threadIdx.x & 63;
  int m = blockIdx.x * 4 + (threadIdx.x >> 6);
  int s = lane >> 3, i = lane & 7;
  int b = 2 * s + (i >> 2), f = (i & 3) * 4;
  float4 v = *(const float4*)(x + (size_t)b * XBS + (size_t)m * FIN + f);
  ushort4 r = make_ushort4(f2bf(v.x), f2bf(v.y), f2bf(v.z), f2bf(v.w));
  *(ushort4*)(x0b + (size_t)s * SLICEB + (size_t)m * 64 + i * 8) = r;
}

// ---------------- CSR build ----------------

__global__ __launch_bounds__(256) void hist_kernel(const int* __restrict__ rows,
                                                   int* __restrict__ counts, int nnz) {
  int i = blockIdx.x * 256 + threadIdx.x;
  if (i < nnz) atomicAdd(&counts[rows[i]], 1);
}

DEVFN int wave_incl_scan(int v, int lane) {
#pragma unroll
  for (int off = 1; off < 64; off <<= 1) {
    int t = __shfl_up(v, off);
    if (lane >= off) v += t;
  }
  return v;
}

// generic: per-block inclusive scan of src -> dst[i+1], block total -> partials
__global__ __launch_bounds__(1024) void scan_blocks(const int* __restrict__ src,
                                                    int* __restrict__ dst,
                                                    int* __restrict__ partials) {
  __shared__ int wsum[16];
  int tid = threadIdx.x, lane = tid & 63, w = tid >> 6;
  int i = blockIdx.x * 1024 + tid;
  int s = wave_incl_scan(src[i], lane);
  if (lane == 63) wsum[w] = s;
  __syncthreads();
  if (tid < 16) {
    int t = wsum[tid];
#pragma unroll
    for (int off = 1; off < 16; off <<= 1) {
      int u = __shfl_up(t, off);
      if (tid >= off) t += u;
    }
    wsum[tid] = t;
  }
  __syncthreads();
  int base = (w > 0) ? wsum[w - 1] : 0;
  s += base;
  dst[i + 1] = s;
  if (tid == 1023) partials[blockIdx.x] = s;
}

__global__ void scan_partials_kernel(int* __restrict__ partials,
                                     int* __restrict__ dst, int nblk) {
  int lane = threadIdx.x;  // 64 threads
  int v = (lane < nblk) ? partials[lane] : 0;
  v = wave_incl_scan(v, lane);
  if (lane < nblk) partials[lane] = v;
  if (lane == 0) dst[0] = 0;
}

__global__ __launch_bounds__(1024) void scan_add_kernel(int* __restrict__ dst,
                                                        const int* __restrict__ partials) {
  if (blockIdx.x == 0) return;
  int i = blockIdx.x * 1024 + threadIdx.x;
  dst[i + 1] += partials[blockIdx.x - 1];
}

// cv entry: col (high 16) | val-bf16 (low 16)
__global__ __launch_bounds__(256) void scatter_kernel(const int* __restrict__ rows,
                                                      const int* __restrict__ cols,
                                                      const float* __restrict__ vals,
                                                      const int* __restrict__ row_ptr,
                                                      int* __restrict__ fill,
                                                      u32* __restrict__ cvp, int nnz) {
  int i = blockIdx.x * 256 + threadIdx.x;
  if (i < nnz) {
    int r = rows[i];
    int pos = row_ptr[r] + atomicAdd(&fill[r], 1);
    cvp[pos] = ((u32)cols[i] << 16) | (u32)f2bf(vals[i]);
  }
}

// ---------------- degree counting sort (contention-free) ----------------
// Pass A: per-block LDS hist -> blkhist[bin*192 + blk] (bin-major).
// Pass B: exclusive scan of the 12288 entries (scan_blocks trio).
// Pass C: per-block LDS local ranks -> perm[sc[bin*192+blk] + rank] = m.

__global__ __launch_bounds__(256) void deg_hist_blk(const int* __restrict__ counts,
                                                    int* __restrict__ blkhist) {
  __shared__ int lh[64];
  int tid = threadIdx.x;
  if (tid < 64) lh[tid] = 0;
  __syncthreads();
  int m = blockIdx.x * 256 + tid;
  atomicAdd(&lh[min(counts[m], 63)], 1);
  __syncthreads();
  if (tid < 64) blkhist[tid * NBLK_M + blockIdx.x] = lh[tid];
}

__global__ __launch_bounds__(256) void perm_scatter_blk(const int* __restrict__ counts,
                                                        const int* __restrict__ sc,
                                                        int* __restrict__ perm) {
  __shared__ int lh[64];
  __shared__ int lbase[64];
  int tid = threadIdx.x, blk = blockIdx.x;
  if (tid < 64) lh[tid] = 0;
  __syncthreads();
  int m = blk * 256 + tid;
  int d = min(counts[m], 63);
  int lr = atomicAdd(&lh[d], 1);          // LDS-local rank
  __syncthreads();
  if (tid < 64) lbase[tid] = sc[tid * NBLK_M + blk];
  __syncthreads();
  perm[lbase[d] + lr] = m;
}

// ---------------- SpMM: XCD-sliced, strip-loaded, reduce-free ----------------
// slice s = blockIdx&7 (-> XCD). Wave = 8 rows x 8 q-chunks; lane (r,q) owns
// features q*4..q*4+3 of row perm[grp*8+r]. Per 8 edges: lane loads ONE cv
// word (edge t0+q of its row, coalesced strip), then 8 __shfl broadcasts feed
// 8 fully-unrolled independent gathers. cvw=0 pad -> exact zero contribution.

template <bool SUB>
__global__ __launch_bounds__(256) void spmm_strip(const char* __restrict__ xsrc,
                                                  const char* __restrict__ ssrc,
                                                  char* __restrict__ y,
                                                  const int* __restrict__ row_ptr,
                                                  const int* __restrict__ degs,
                                                  const int* __restrict__ perm,
                                                  const u32* __restrict__ cvp) {
  int s  = blockIdx.x & 7;
  int g4 = blockIdx.x >> 3;
  int lane = threadIdx.x & 63, wave = threadIdx.x >> 6;
  int r = lane >> 3, q = lane & 7;
  int rq = lane & 56;                      // r*8
  int grp = g4 * 4 + wave;                 // row-group (8 rows)
  const char* sbase = xsrc + (size_t)s * SLICEB;
  size_t qb = (size_t)q * 8;

  int rid  = perm[grp * 8 + r];            // broadcast over q
  int base = row_ptr[rid];
  int deg  = degs[rid];
  int wmax = deg;
  wmax = max(wmax, __shfl_xor(wmax, 8));
  wmax = max(wmax, __shfl_xor(wmax, 16));
  wmax = max(wmax, __shfl_xor(wmax, 32));

  u64 sv = 0;
  if (SUB)
    sv = __builtin_nontemporal_load(
        (const u64*)(ssrc + (size_t)s * SLICEB + (size_t)rid * 64 + qb));

  float a0 = 0.f, a1 = 0.f, a2 = 0.f, a3 = 0.f;
  for (int t0 = 0; t0 < wmax; t0 += 8) {
    int et = t0 + q;
    u32 cvw = 0u;
    if (et < deg) cvw = cvp[base + et];    // exec-masked load, 32B/row strip
#pragma unroll
    for (int t = 0; t < 8; ++t) {
      u32 c = (u32)__shfl((int)cvw, rq | t);
      u64 d = *(const u64*)(sbase + (size_t)(c >> 16) * 64 + qb);
      float v = lo2f(c);
      u32 dl = (u32)d, dh = (u32)(d >> 32);
      a0 = fmaf(v, lo2f(dl), a0); a1 = fmaf(v, hi2f(dl), a1);
      a2 = fmaf(v, lo2f(dh), a2); a3 = fmaf(v, hi2f(dh), a3);
    }
  }

  if (SUB) {
    u32 sl = (u32)sv, sh = (u32)(sv >> 32);
    a0 = fmaf(2.f, a0, -lo2f(sl)); a1 = fmaf(2.f, a1, -hi2f(sl));
    a2 = fmaf(2.f, a2, -lo2f(sh)); a3 = fmaf(2.f, a3, -hi2f(sh));
  }
  u64 rv = ((u64)(((u32)f2bf(a3) << 16) | (u32)f2bf(a2)) << 32) |
           (u64)(((u32)f2bf(a1) << 16) | (u32)f2bf(a0));
  __builtin_nontemporal_store(
      rv, (u64*)(y + (size_t)s * SLICEB + (size_t)rid * 64 + qb));
}

// ---------------- Final contraction via MFMA ----------------
// out[(b*M+m)*32+o] = sum_{k,f} xs_k[m][b*16+f] * kern[(f*5+k)*32+o] + bias[o]
// kk = c*32 + g*8 + j <-> k = 2c+(g>>1), f = (g&1)*8+j; 3 chunks of K=32.
// Slice layout: feature b*16+f lives in slice b>>1 at byte (b&1)*32+f*2.

__global__ __launch_bounds__(256) void cheb_gemm_mfma(const char* __restrict__ xs0,
                                                      const float* __restrict__ kern,
                                                      const float* __restrict__ bias,
                                                      float* __restrict__ out) {
  __shared__ unsigned short bl[3][4][32][8];  // [c][g][o][j] = B_kk,o  (6 KB)
  __shared__ float bsl[32];
  int tid = threadIdx.x;
  for (int idx = tid; idx < 3 * 4 * 32 * 8; idx += 256) {
    int j = idx & 7, o = (idx >> 3) & 31, g = (idx >> 8) & 3, c = idx >> 10;
    int k = 2 * c + (g >> 1), f = (g & 1) * 8 + j;
    bl[c][g][o][j] = (k < K) ? f2bf(kern[(f * K + k) * F1 + o]) : (unsigned short)0;
  }
  if (tid < 32) bsl[tid] = bias[tid];
  __syncthreads();

  int lane = tid & 63;
  int w = blockIdx.x * 4 + (tid >> 6);     // 0..6143
  int b = w / 384;                         // 384 waves per batch b
  int mt0 = (w % 384) * 8;                 // first 16-row m-tile of 8

  int row = lane & 15, g = lane >> 4;
  int col = lane & 15;

  s16x8 bf[3][2];
#pragma unroll
  for (int c = 0; c < 3; ++c) {
#pragma unroll
    for (int ot = 0; ot < 2; ++ot)
      bf[c][ot] = *(const s16x8*)(&bl[c][g][col + 16 * ot][0]);
  }
  float bias0 = bsl[col], bias1 = bsl[col + 16];

  size_t lanebyte = (size_t)(b >> 1) * SLICEB + (size_t)row * 64 +
                    (size_t)(b & 1) * 32 + (size_t)(g & 1) * 16;
  int khalf = g >> 1;
  const char* p0 = xs0 + (size_t)(0 + khalf) * BUFBYTES + lanebyte;
  const char* p1 = xs0 + (size_t)(2 + khalf) * BUFBYTES + lanebyte;
  const char* p2 = xs0 + (size_t)(4 + khalf) * BUFBYTES + lanebyte;  // valid g<2

  size_t obase0 = ((size_t)b * M + (size_t)mt0 * 16) * F1;

#pragma unroll 2
  for (int t = 0; t < 8; ++t) {
    size_t moff = (size_t)(mt0 + t) * (16 * 64);
    s16x8 a0 = *(const s16x8*)(p0 + moff);
    s16x8 a1 = *(const s16x8*)(p1 + moff);
    s16x8 a2 = (g < 2) ? *(const s16x8*)(p2 + moff) : (s16x8)0;

    f32x4 acc0 = {0.f, 0.f, 0.f, 0.f};
    f32x4 acc1 = {0.f, 0.f, 0.f, 0.f};
    acc0 = __builtin_amdgcn_mfma_f32_16x16x32_bf16(a0, bf[0][0], acc0, 0, 0, 0);
    acc1 = __builtin_amdgcn_mfma_f32_16x16x32_bf16(a0, bf[0][1], acc1, 0, 0, 0);
    acc0 = __builtin_amdgcn_mfma_f32_16x16x32_bf16(a1, bf[1][0], acc0, 0, 0, 0);
    acc1 = __builtin_amdgcn_mfma_f32_16x16x32_bf16(a1, bf[1][1], acc1, 0, 0, 0);
    acc0 = __builtin_amdgcn_mfma_f32_16x16x32_bf16(a2, bf[2][0], acc0, 0, 0, 0);
    acc1 = __builtin_amdgcn_mfma_f32_16x16x32_bf16(a2, bf[2][1], acc1, 0, 0, 0);

    float* ob = out + obase0 + (size_t)t * (16 * F1);
#pragma unroll
    for (int j = 0; j < 4; ++j) {
      int r = g * 4 + j;
      __builtin_nontemporal_store(acc0[j] + bias0, ob + r * F1 + col);
      __builtin_nontemporal_store(acc1[j] + bias1, ob + r * F1 + col + 16);
    }
  }
}

// ---------------- launch ----------------

extern "C" void kernel_launch(void* const* d_in, const int* in_sizes, int n_in,
                              void* d_out, int out_size, void* d_ws, size_t ws_size,
                              hipStream_t stream) {
  const float* x    = (const float*)d_in[0];
  const int*   rows = (const int*)d_in[1];
  const int*   cols = (const int*)d_in[2];
  const float* vals = (const float*)d_in[3];
  const float* kern = (const float*)d_in[4];
  const float* bias = (const float*)d_in[5];
  float* out = (float*)d_out;
  int nnz = in_sizes[1];

  // workspace layout (~123 MiB); xs buffers contiguous, each slice-major.
  char* x0b = (char*)d_ws;
  char* x1b = x0b + BUFBYTES;
  char* x2b = x1b + BUFBYTES;
  char* x3b = x2b + BUFBYTES;
  char* x4b = x3b + BUFBYTES;
  int* row_ptr  = (int*)(x4b + BUFBYTES);         // M+1 (padded to M+256)
  int* counts   = row_ptr + (M + 256);            // M  (degree array)
  int* fill     = counts + M;                     // M  (scatter cursor)
  int* partials = fill + M;                       // 64 (padded to 256; scan scratch)
  int* blkhist  = partials + 256;                 // 12288 bin-major hist
  int* sc       = blkhist + NHB;                  // 12288+1 exclusive offsets (pad 256)
  int* perm     = sc + NHB + 256;                 // M
  u32* cvp      = (u32*)(perm + M);               // NNZ packed (col<<16|val-bf16)

  int nblk1024 = M / 1024;                        // 48
  int nblkH    = NHB / 1024;                      // 12
  int nblkNnz  = (nnz + 255) / 256;

  transform_x<<<M / 4, 256, 0, stream>>>(x, x0b);

  hipMemsetAsync(counts, 0, (size_t)2 * M * 4, stream);   // counts + fill
  hist_kernel<<<nblkNnz, 256, 0, stream>>>(rows, counts, nnz);
  // row_ptr = exclusive scan of counts
  scan_blocks<<<nblk1024, 1024, 0, stream>>>(counts, row_ptr, partials);
  scan_partials_kernel<<<1, 64, 0, stream>>>(partials, row_ptr, nblk1024);
  scan_add_kernel<<<nblk1024, 1024, 0, stream>>>(row_ptr, partials);
  // degree counting sort -> perm
  deg_hist_blk<<<NBLK_M, 256, 0, stream>>>(counts, blkhist);
  scan_blocks<<<nblkH, 1024, 0, stream>>>(blkhist, sc, partials);
  scan_partials_kernel<<<1, 64, 0, stream>>>(partials, sc, nblkH);
  scan_add_kernel<<<nblkH, 1024, 0, stream>>>(sc, partials);
  perm_scatter_blk<<<NBLK_M, 256, 0, stream>>>(counts, sc, perm);
  // CSR scatter
  scatter_kernel<<<nblkNnz, 256, 0, stream>>>(rows, cols, vals, row_ptr, fill, cvp, nnz);

  // Chebyshev recurrence (bf16, slice-major, fp32 accumulate)
  int spmmGrid = 8 * (M / 32);                    // 12288 blocks
  spmm_strip<false><<<spmmGrid, 256, 0, stream>>>(x0b, nullptr, x1b, row_ptr, counts, perm, cvp);
  spmm_strip<true ><<<spmmGrid, 256, 0, stream>>>(x1b, x0b, x2b, row_ptr, counts, perm, cvp);
  spmm_strip<true ><<<spmmGrid, 256, 0, stream>>>(x2b, x1b, x3b, row_ptr, counts, perm, cvp);
  spmm_strip<true ><<<spmmGrid, 256, 0, stream>>>(x3b, x2b, x4b, row_ptr, counts, perm, cvp);

  // final contraction + bias via MFMA: 1536 blocks x 4 waves x 8 m-tiles
  cheb_gemm_mfma<<<1536, 256, 0, stream>>>(x0b, kern, bias, out);

  (void)n_in; (void)out_size; (void)ws_size; (void)in_sizes;
}